// Round 4
// baseline (766.247 us; speedup 1.0000x reference)
//
#include <hip/hip_runtime.h>
#include <stdint.h>

// D = 4096, TOKENS = (4,2048) -> M = 8192.
#define DD 4096
#define NE_IDX 3277   // round(4096*0.8)

typedef __attribute__((ext_vector_type(8))) short short8;
typedef __attribute__((ext_vector_type(4))) float f32x4;
typedef __attribute__((ext_vector_type(16))) float f32x16;
typedef __attribute__((ext_vector_type(4))) unsigned int u32x4;

__device__ __forceinline__ unsigned short f2bf(float f) {
    unsigned int u = __float_as_uint(f);
    u += 0x7fffu + ((u >> 16) & 1u);
    return (unsigned short)(u >> 16);
}

__device__ __forceinline__ void gload16(const void* g, void* l) {
    __builtin_amdgcn_global_load_lds(
        (const __attribute__((address_space(1))) unsigned int*)g,
        (__attribute__((address_space(3))) unsigned int*)l,
        16, 0, 0);
}

// ---------------------------------------------------------------------------
__global__ void detect_kernel(const unsigned int* __restrict__ k0, int* __restrict__ flag) {
    if (blockIdx.x == 0 && threadIdx.x == 0) {
        int ok4 = 1;
        for (int i = 0; i < 256; ++i) {
            unsigned int v = k0[i];
            if (!(v == 0u || v == 1u || v == 0x3f800000u)) { ok4 = 0; break; }
        }
        *flag = ok4;
    }
}

// ---------------------------------------------------------------------------
__global__ void pack_x_kernel(const float* __restrict__ x, unsigned short* __restrict__ xb, int n8) {
    const int stride = gridDim.x * blockDim.x;
    for (int i = blockIdx.x * blockDim.x + threadIdx.x; i < n8; i += stride) {
        const float4* p = (const float4*)(x + (size_t)i * 8);
        float4 a = p[0], b = p[1];
        short8 r;
        r[0] = (short)f2bf(a.x); r[1] = (short)f2bf(a.y);
        r[2] = (short)f2bf(a.z); r[3] = (short)f2bf(a.w);
        r[4] = (short)f2bf(b.x); r[5] = (short)f2bf(b.y);
        r[6] = (short)f2bf(b.z); r[7] = (short)f2bf(b.w);
        *(short8*)(xb + (size_t)i * 8) = r;
    }
}

// ---------------------------------------------------------------------------
// wt[j*DD + i] = s * (i < ne ? 1 : inh) * (k[i][j] ? 1 : -1), 64x64 LDS transpose
// ---------------------------------------------------------------------------
__global__ void pack_w_kernel(const void* __restrict__ kin, unsigned short* __restrict__ wt,
                              const float* __restrict__ sptr, float inh, int ne,
                              const int* __restrict__ flag) {
    __shared__ unsigned short tile[64][68];
    const int elem4 = *flag;
    const float s = *sptr;
    const int i0 = blockIdx.x * 64;
    const int j0 = blockIdx.y * 64;
    const int t = threadIdx.x;
    {
        const int il = t >> 2;
        const int jc = (t & 3) * 16;
        const int gi = i0 + il;
        const float mag = s * ((gi < ne) ? 1.0f : inh);
        const unsigned short pos = f2bf(mag);
        const unsigned short neg = f2bf(-mag);
        if (elem4) {
            const unsigned int* k32 = (const unsigned int*)kin + (size_t)gi * DD + j0 + jc;
            #pragma unroll
            for (int q = 0; q < 4; ++q) {
                u32x4 v = *(const u32x4*)(k32 + q * 4);
                #pragma unroll
                for (int e = 0; e < 4; ++e)
                    tile[il][jc + q * 4 + e] = v[e] ? pos : neg;
            }
        } else {
            const unsigned char* k8 = (const unsigned char*)kin + (size_t)gi * DD + j0 + jc;
            u32x4 v = *(const u32x4*)k8;
            #pragma unroll
            for (int q = 0; q < 4; ++q) {
                unsigned int w = v[q];
                tile[il][jc + q * 4 + 0] = (w & 0xffu) ? pos : neg;
                tile[il][jc + q * 4 + 1] = ((w >> 8) & 0xffu) ? pos : neg;
                tile[il][jc + q * 4 + 2] = ((w >> 16) & 0xffu) ? pos : neg;
                tile[il][jc + q * 4 + 3] = ((w >> 24) & 0xffu) ? pos : neg;
            }
        }
    }
    __syncthreads();
    {
        const int jl = t >> 2;
        const int ic = (t & 3) * 16;
        short8 o0, o1;
        #pragma unroll
        for (int e = 0; e < 8; ++e) o0[e] = (short)tile[ic + e][jl];
        #pragma unroll
        for (int e = 0; e < 8; ++e) o1[e] = (short)tile[ic + 8 + e][jl];
        unsigned short* dst = wt + (size_t)(j0 + jl) * DD + i0 + ic;
        *(short8*)(dst) = o0;
        *(short8*)(dst + 8) = o1;
    }
}

// ---------------------------------------------------------------------------
// 256x256 tile, BK=64, 8 waves (2Mx4N), 4 phases/K-tile, 32x32x16 MFMA.
// Per wave: 128x64 output = 4 m-tiles (32 rows) x 2 n-tiles (32 cols).
// Phase order (0,0),(0,1),(1,1),(1,0): A-half (2 m-tiles, 8 frags) reused
// across phase pairs, B n-tile (4 frags) shared by middle pair.
// Per phase: [frag reads] -> stage 1 chunk -> vmcnt(4) -> barrier ->
// lgkmcnt(0) -> 8 MFMA (setprio) -> fence. End-barrier only at p3.
// vmcnt deadline proof identical to round 3 (staging untouched).
// Frag layout 32x32x16: A row=lane&31, k=8*(lane>>5)+e; B col=lane&31, same k.
// addr = base[t] ^ (s<<5), base = r*128 + (((lane>>5)^(r&7))<<4)  (swizzle).
// C/D: col=lane&31, row=(reg&3)+8*(reg>>2)+4*(lane>>5).
// ---------------------------------------------------------------------------
#define PH32(MH, NH, LA, LB, STAGE_STMT, EB) do {                               \
    if (LA) {                                                                   \
        _Pragma("unroll")                                                       \
        for (int mi = 0; mi < 2; ++mi)                                          \
            _Pragma("unroll")                                                   \
            for (int s = 0; s < 4; ++s)                                         \
                af[mi][s] = *(const short8*)(Lc + (abh[(MH)*2+mi] ^ (s<<5)));   \
    }                                                                           \
    if (LB) {                                                                   \
        _Pragma("unroll")                                                       \
        for (int s = 0; s < 4; ++s)                                             \
            bf[s] = *(const short8*)(Lc + (bbh[(NH)] ^ (s<<5)));                \
    }                                                                           \
    STAGE_STMT;                                                                 \
    asm volatile("s_waitcnt vmcnt(4)" ::: "memory");                            \
    __builtin_amdgcn_s_barrier();                                               \
    asm volatile("s_waitcnt lgkmcnt(0)" ::: "memory");                          \
    __builtin_amdgcn_sched_barrier(0);                                          \
    __builtin_amdgcn_s_setprio(1);                                              \
    _Pragma("unroll")                                                           \
    for (int s = 0; s < 4; ++s)                                                 \
        _Pragma("unroll")                                                       \
        for (int mi = 0; mi < 2; ++mi)                                          \
            acc[(MH)*2+mi][(NH)] = __builtin_amdgcn_mfma_f32_32x32x16_bf16(     \
                af[mi][s], bf[s], acc[(MH)*2+mi][(NH)], 0, 0, 0);               \
    __builtin_amdgcn_s_setprio(0);                                              \
    __builtin_amdgcn_sched_barrier(0);                                          \
    if (EB) __builtin_amdgcn_s_barrier();                                       \
} while (0)

template <int MODE>
__global__ __launch_bounds__(512, 2)
void gemm256_kernel(const unsigned short* __restrict__ A,   // M x 4096 bf16
                    const unsigned short* __restrict__ Bt,  // 4096 x 4096 bf16 (N x K)
                    void* __restrict__ Cout)
{
    __shared__ unsigned short L[65536];  // 128 KiB: buf0{A,B} buf1{A,B}
    const char* Lc = (const char*)L;

    const int tid  = threadIdx.x;
    const int lane = tid & 63;
    const int l31  = lane & 31;
    const int hb   = lane >> 5;          // k-half select
    const int wave = tid >> 6;
    const int wr   = wave >> 2;    // 0..1
    const int wc   = wave & 3;     // 0..3

    // XCD swizzle (grid = 512, divisible by 8)
    int wg = blockIdx.x;
    const int per = gridDim.x >> 3;
    wg = (wg & 7) * per + (wg >> 3);
    const int tm = wg >> 4;        // 32 M-tiles
    const int tn = wg & 15;        // 16 N-tiles

    const size_t arow0 = (size_t)tm * 256;
    const size_t brow0 = (size_t)tn * 256;

    // staging: thread tid handles round-row rq = tid>>3, 16B chunk tid&7.
    const int rq = tid >> 3;
    const int wq = (tid >> 6) << 3;
    const int srcoff = (((tid & 7) ^ ((tid >> 3) & 7)) << 3);

    auto stageA = [&](int sb, int c, int kt) {
        #pragma unroll
        for (int q = 0; q < 2; ++q) {
            const int dr = c * 64 + q * 128 + rq;
            gload16(A + ((arow0 + dr) << 12) + kt + srcoff,
                    (void*)&L[sb + ((c * 64 + q * 128 + wq) << 6)]);
        }
    };
    auto stageB = [&](int sb, int c, int kt) {
        #pragma unroll
        for (int q = 0; q < 2; ++q) {
            const int lr  = q * 64 + rq;
            const int dr  = c * 32 + (lr & 31) + (lr >> 5) * 64;
            const int wlr = q * 64 + wq;
            const int wdr = c * 32 + (wlr & 31) + (wlr >> 5) * 64;
            gload16(Bt + ((brow0 + dr) << 12) + kt + srcoff,
                    (void*)&L[sb + 16384 + (wdr << 6)]);
        }
    };

    // precomputed ds_read byte bases (swizzle + k-half + buffer bit folded in)
    int abh[4], bbh[2];
    #pragma unroll
    for (int mt = 0; mt < 4; ++mt) {
        const int r = wr * 128 + mt * 32 + l31;
        abh[mt] = r * 128 + ((hb ^ (r & 7)) << 4);
    }
    #pragma unroll
    for (int nt = 0; nt < 2; ++nt) {
        const int r = wc * 64 + nt * 32 + l31;
        bbh[nt] = 32768 + r * 128 + ((hb ^ (r & 7)) << 4);
    }

    short8 af[2][4], bf[4];
    f32x16 acc[4][2];
    #pragma unroll
    for (int m = 0; m < 4; ++m)
        #pragma unroll
        for (int n = 0; n < 2; ++n)
            #pragma unroll
            for (int e = 0; e < 16; ++e)
                acc[m][n][e] = 0.f;

    // prologue: tile 0 into buf0; vmcnt(4) leaves newest {B1,A1} in flight
    stageA(0, 0, 0); stageB(0, 0, 0); stageB(0, 1, 0); stageA(0, 1, 0);
    asm volatile("s_waitcnt vmcnt(4)" ::: "memory");
    __builtin_amdgcn_s_barrier();
    __builtin_amdgcn_sched_barrier(0);

    for (int t = 0; t < 63; ++t) {
        const int sb  = ((t & 1) ^ 1) * 32768;  // u16 index of stage buffer
        const int kt1 = (t + 1) * 64;
        PH32(0, 0, 1, 1, stageA(sb, 0, kt1), 0);
        PH32(0, 1, 0, 1, stageB(sb, 0, kt1), 0);
        PH32(1, 1, 1, 0, stageB(sb, 1, kt1), 0);
        PH32(1, 0, 0, 1, stageA(sb, 1, kt1), 1);
        #pragma unroll
        for (int i = 0; i < 4; ++i) abh[i] ^= 65536;
        bbh[0] ^= 65536; bbh[1] ^= 65536;
    }
    // tail tile 63 (bases already point at buf1), no staging
    asm volatile("s_waitcnt vmcnt(0)" ::: "memory");
    __builtin_amdgcn_s_barrier();
    __builtin_amdgcn_sched_barrier(0);
    PH32(0, 0, 1, 1, (void)0, 0);
    PH32(0, 1, 0, 1, (void)0, 0);
    PH32(1, 1, 1, 0, (void)0, 0);
    PH32(1, 0, 0, 1, (void)0, 0);

    // epilogue: C/D col = lane&31, row = (reg&3) + 8*(reg>>2) + 4*(lane>>5)
    const int orow0 = tm * 256 + wr * 128 + hb * 4;
    const int ocol0 = tn * 256 + wc * 64 + l31;
    #pragma unroll
    for (int mt = 0; mt < 4; ++mt) {
        #pragma unroll
        for (int nt = 0; nt < 2; ++nt) {
            #pragma unroll
            for (int reg = 0; reg < 16; ++reg) {
                const int row = orow0 + mt * 32 + (reg & 3) + 8 * (reg >> 2);
                const int col = ocol0 + nt * 32;
                float v = acc[mt][nt][reg];
                if (MODE == 1) {
                    v = fmaxf(v, 0.0f) * 2.0f;
                    ((unsigned short*)Cout)[((size_t)row << 12) + col] = f2bf(v);
                } else {
                    ((float*)Cout)[((size_t)row << 12) + col] = v;
                }
            }
        }
    }
}

// ---------------------------------------------------------------------------
extern "C" void kernel_launch(void* const* d_in, const int* in_sizes, int n_in,
                              void* d_out, int out_size, void* d_ws, size_t ws_size,
                              hipStream_t stream) {
    const float* x  = (const float*)d_in[0];
    const void*  k0 = d_in[1];
    const float* s0 = (const float*)d_in[2];
    const void*  k1 = d_in[3];
    const float* s1 = (const float*)d_in[4];
    const void*  k2 = d_in[5];
    const float* s2 = (const float*)d_in[6];

    const int M = in_sizes[0] / DD;   // 8192

    const size_t act_bytes = (size_t)M * DD * 2;
    const size_t w_bytes   = (size_t)DD * DD * 2;
    const size_t need      = act_bytes * 2 + w_bytes + 256;
    if (ws_size < need) return;

    char* ws = (char*)d_ws;
    unsigned short* xb = (unsigned short*)ws;                        // M x DD bf16 (later h2)
    unsigned short* h1 = (unsigned short*)(ws + act_bytes);          // M x DD bf16
    unsigned short* wt = (unsigned short*)(ws + act_bytes * 2);      // DD x DD bf16 (N x K)
    int* flag          = (int*)(ws + act_bytes * 2 + w_bytes);

    detect_kernel<<<1, 64, 0, stream>>>((const unsigned int*)k0, flag);
    pack_x_kernel<<<2048, 256, 0, stream>>>(x, xb, M * DD / 8);

    dim3 pw_grid(DD / 64, DD / 64);
    const int gemm_grid = (M / 256) * (DD / 256);   // 512

    // layer 0: h1 = relu(s0 * x @ W0) * 2
    pack_w_kernel<<<pw_grid, 256, 0, stream>>>(k0, wt, s0, 1.0f, DD, flag);
    gemm256_kernel<1><<<gemm_grid, 512, 0, stream>>>(xb, wt, h1);

    // layer 1: h2 = relu(ei_dense(h1, k1, s1)) * 2
    pack_w_kernel<<<pw_grid, 256, 0, stream>>>(k1, wt, s1, -4.0f, NE_IDX, flag);
    gemm256_kernel<1><<<gemm_grid, 512, 0, stream>>>(h1, wt, xb);

    // layer 2: out = ei_dense(h2, k2, s2), fp32
    pack_w_kernel<<<pw_grid, 256, 0, stream>>>(k2, wt, s2, -4.0f, NE_IDX, flag);
    gemm256_kernel<0><<<gemm_grid, 512, 0, stream>>>(xb, wt, (float*)d_out);
}

// Round 5
// 733.487 us; speedup vs baseline: 1.0447x; 1.0447x over previous
//
#include <hip/hip_runtime.h>
#include <stdint.h>

// D = 4096, TOKENS = (4,2048) -> M = 8192.
#define DD 4096
#define NE_IDX 3277   // round(4096*0.8)

typedef __attribute__((ext_vector_type(8))) short short8;
typedef __attribute__((ext_vector_type(16))) float f32x16;
typedef __attribute__((ext_vector_type(4))) unsigned int u32x4;

__device__ __forceinline__ unsigned short f2bf(float f) {
    unsigned int u = __float_as_uint(f);
    u += 0x7fffu + ((u >> 16) & 1u);
    return (unsigned short)(u >> 16);
}

__device__ __forceinline__ void gload16(const void* g, void* l) {
    __builtin_amdgcn_global_load_lds(
        (const __attribute__((address_space(1))) unsigned int*)g,
        (__attribute__((address_space(3))) unsigned int*)l,
        16, 0, 0);
}

// ---------------------------------------------------------------------------
__global__ void detect_kernel(const unsigned int* __restrict__ k0, int* __restrict__ flag) {
    if (blockIdx.x == 0 && threadIdx.x == 0) {
        int ok4 = 1;
        for (int i = 0; i < 256; ++i) {
            unsigned int v = k0[i];
            if (!(v == 0u || v == 1u || v == 0x3f800000u)) { ok4 = 0; break; }
        }
        *flag = ok4;
    }
}

// ---------------------------------------------------------------------------
__global__ void pack_x_kernel(const float* __restrict__ x, unsigned short* __restrict__ xb, int n8) {
    const int stride = gridDim.x * blockDim.x;
    for (int i = blockIdx.x * blockDim.x + threadIdx.x; i < n8; i += stride) {
        const float4* p = (const float4*)(x + (size_t)i * 8);
        float4 a = p[0], b = p[1];
        short8 r;
        r[0] = (short)f2bf(a.x); r[1] = (short)f2bf(a.y);
        r[2] = (short)f2bf(a.z); r[3] = (short)f2bf(a.w);
        r[4] = (short)f2bf(b.x); r[5] = (short)f2bf(b.y);
        r[6] = (short)f2bf(b.z); r[7] = (short)f2bf(b.w);
        *(short8*)(xb + (size_t)i * 8) = r;
    }
}

// ---------------------------------------------------------------------------
// wt[j*DD + i] = s * (i < ne ? 1 : inh) * (k[i][j] ? 1 : -1), 64x64 LDS transpose
// ---------------------------------------------------------------------------
__global__ void pack_w_kernel(const void* __restrict__ kin, unsigned short* __restrict__ wt,
                              const float* __restrict__ sptr, float inh, int ne,
                              const int* __restrict__ flag) {
    __shared__ unsigned short tile[64][68];
    const int elem4 = *flag;
    const float s = *sptr;
    const int i0 = blockIdx.x * 64;
    const int j0 = blockIdx.y * 64;
    const int t = threadIdx.x;
    {
        const int il = t >> 2;
        const int jc = (t & 3) * 16;
        const int gi = i0 + il;
        const float mag = s * ((gi < ne) ? 1.0f : inh);
        const unsigned short pos = f2bf(mag);
        const unsigned short neg = f2bf(-mag);
        if (elem4) {
            const unsigned int* k32 = (const unsigned int*)kin + (size_t)gi * DD + j0 + jc;
            #pragma unroll
            for (int q = 0; q < 4; ++q) {
                u32x4 v = *(const u32x4*)(k32 + q * 4);
                #pragma unroll
                for (int e = 0; e < 4; ++e)
                    tile[il][jc + q * 4 + e] = v[e] ? pos : neg;
            }
        } else {
            const unsigned char* k8 = (const unsigned char*)kin + (size_t)gi * DD + j0 + jc;
            u32x4 v = *(const u32x4*)k8;
            #pragma unroll
            for (int q = 0; q < 4; ++q) {
                unsigned int w = v[q];
                tile[il][jc + q * 4 + 0] = (w & 0xffu) ? pos : neg;
                tile[il][jc + q * 4 + 1] = ((w >> 8) & 0xffu) ? pos : neg;
                tile[il][jc + q * 4 + 2] = ((w >> 16) & 0xffu) ? pos : neg;
                tile[il][jc + q * 4 + 3] = ((w >> 24) & 0xffu) ? pos : neg;
            }
        }
    }
    __syncthreads();
    {
        const int jl = t >> 2;
        const int ic = (t & 3) * 16;
        short8 o0, o1;
        #pragma unroll
        for (int e = 0; e < 8; ++e) o0[e] = (short)tile[ic + e][jl];
        #pragma unroll
        for (int e = 0; e < 8; ++e) o1[e] = (short)tile[ic + 8 + e][jl];
        unsigned short* dst = wt + (size_t)(j0 + jl) * DD + i0 + ic;
        *(short8*)(dst) = o0;
        *(short8*)(dst + 8) = o1;
    }
}

// ---------------------------------------------------------------------------
// 256x256 tile, BK=64, 8 waves (2Mx4N), 4 phases/K-tile, 32x32x16 MFMA.
// LDS geometry: "double-row" layout. A-tile (256 rows x 64k) = 128 drows x
// 256B; drow d holds rows {2d, 2d+1}; 16B slot index:
//     slot = (kc | rbit<<3) ^ (d & 15)      (kc = k>>3, rbit = row&1)
// -> a 32-row fragment read (ds_read_b128, fixed kc) maps every addr/16 mod 32
//    bank-quad to exactly 2 lanes: conflict-free (2-way is free, m136).
// -> staging stays linear 1024B/wave for global_load_lds; the inverse
//    permutation is applied to the per-lane GLOBAL source address, whose
//    per-wave address set is still 8 rows x 128B contiguous (coalesced).
// B-frags persist in regs across the tile: 24 ds_read_b128/tile (minimum).
// Phases (MH,NH): (0,0),(0,1),(1,1),(1,0); reads: 12/4/8/0.
// Stage order A0',B0',B1',A1' at p0..p3; per-phase vmcnt(4) deadline proof
// identical to round 3. End-barrier only at p3.
// ---------------------------------------------------------------------------
#define PH32(MH, NH, LA, LB, STAGE_STMT, EB) do {                               \
    if (LA) {                                                                   \
        _Pragma("unroll")                                                       \
        for (int mi = 0; mi < 2; ++mi)                                          \
            _Pragma("unroll")                                                   \
            for (int s = 0; s < 4; ++s)                                         \
                af[mi][s] = *(const short8*)(Lc + (ab2[(MH)*2+mi] ^ (s<<5)));   \
    }                                                                           \
    if (LB) {                                                                   \
        _Pragma("unroll")                                                       \
        for (int s = 0; s < 4; ++s)                                             \
            bf[(NH)][s] = *(const short8*)(Lc + (bb2[(NH)] ^ (s<<5)));          \
    }                                                                           \
    STAGE_STMT;                                                                 \
    asm volatile("s_waitcnt vmcnt(4)" ::: "memory");                            \
    __builtin_amdgcn_s_barrier();                                               \
    asm volatile("s_waitcnt lgkmcnt(0)" ::: "memory");                          \
    __builtin_amdgcn_sched_barrier(0);                                          \
    __builtin_amdgcn_s_setprio(1);                                              \
    _Pragma("unroll")                                                           \
    for (int s = 0; s < 4; ++s)                                                 \
        _Pragma("unroll")                                                       \
        for (int mi = 0; mi < 2; ++mi)                                          \
            acc[(MH)*2+mi][(NH)] = __builtin_amdgcn_mfma_f32_32x32x16_bf16(     \
                af[mi][s], bf[(NH)][s], acc[(MH)*2+mi][(NH)], 0, 0, 0);         \
    __builtin_amdgcn_s_setprio(0);                                              \
    __builtin_amdgcn_sched_barrier(0);                                          \
    if (EB) __builtin_amdgcn_s_barrier();                                       \
} while (0)

template <int MODE>
__global__ __launch_bounds__(512, 2)
void gemm256_kernel(const unsigned short* __restrict__ A,   // M x 4096 bf16
                    const unsigned short* __restrict__ Bt,  // 4096 x 4096 bf16 (N x K)
                    void* __restrict__ Cout)
{
    __shared__ unsigned short L[65536];  // 128 KiB: buf0{A,B} buf1{A,B}
    const char* Lc = (const char*)L;

    const int tid  = threadIdx.x;
    const int lane = tid & 63;
    const int l31  = lane & 31;
    const int hb   = lane >> 5;          // k-half select
    const int wave = tid >> 6;
    const int wr   = wave >> 2;    // 0..1
    const int wc   = wave & 3;     // 0..3

    // XCD swizzle (grid = 512, divisible by 8)
    int wg = blockIdx.x;
    const int per = gridDim.x >> 3;
    wg = (wg & 7) * per + (wg >> 3);
    const int tm = wg >> 4;        // 32 M-tiles
    const int tn = wg & 15;        // 16 N-tiles

    const size_t arow0 = (size_t)tm * 256;
    const size_t brow0 = (size_t)tn * 256;

    // --- staging constants (slot involution pre-applied to global source) ---
    const int sx  = (tid & 15) ^ ((tid >> 4) & 15);
    const int kcS = (sx & 7) << 3;                 // k element offset 0..56
    const int rbS = sx >> 3;                       // row parity
    const int arowloc = ((tid >> 4) << 1) + rbS;   // 0..63 within A site
    const int lcl = tid & 255;
    const int seg = tid >> 8;
    const int browloc = ((lcl >> 4) << 1) + rbS;   // 0..31 within B segment

    // A site (c,q): drows [c*32+q*64, +32), global rows c*64+q*128+[0,64)
    auto stageA = [&](int sb, int c, int kt) {
        #pragma unroll
        for (int q = 0; q < 2; ++q) {
            gload16(A + ((arow0 + c * 64 + q * 128 + arowloc) << 12) + kt + kcS,
                    (void*)&L[sb + (c * 32 + q * 64) * 128 + tid * 8]);
        }
    };
    // B site (c,q): drows {c*16+seg*32+q*64}, global cols = drow*2+browloc
    auto stageB = [&](int sb, int c, int kt) {
        #pragma unroll
        for (int q = 0; q < 2; ++q) {
            const int d0 = c * 16 + seg * 32 + q * 64;
            gload16(Bt + ((brow0 + d0 * 2 + browloc) << 12) + kt + kcS,
                    (void*)&L[sb + 16384 + d0 * 128 + lcl * 8]);
        }
    };

    // --- ds_read byte bases (double-row + slot swizzle; step s: XOR s<<5) ---
    const int slot0 = (hb | ((l31 & 1) << 3)) ^ (l31 >> 1);
    int ab2[4], bb2[2];
    #pragma unroll
    for (int mt = 0; mt < 4; ++mt) {
        const int d = wr * 64 + mt * 16 + (l31 >> 1);
        ab2[mt] = (d << 8) + (slot0 << 4);
    }
    #pragma unroll
    for (int nt = 0; nt < 2; ++nt) {
        const int d = wc * 32 + nt * 16 + (l31 >> 1);
        bb2[nt] = 32768 + (d << 8) + (slot0 << 4);
    }

    short8 af[2][4], bf[2][4];
    f32x16 acc[4][2];
    #pragma unroll
    for (int m = 0; m < 4; ++m)
        #pragma unroll
        for (int n = 0; n < 2; ++n)
            #pragma unroll
            for (int e = 0; e < 16; ++e)
                acc[m][n][e] = 0.f;

    // prologue: tile 0 into buf0; vmcnt(4) -> A0,B0 landed ({B1,A1} in flight)
    stageA(0, 0, 0); stageB(0, 0, 0); stageB(0, 1, 0); stageA(0, 1, 0);
    asm volatile("s_waitcnt vmcnt(4)" ::: "memory");
    __builtin_amdgcn_s_barrier();
    __builtin_amdgcn_sched_barrier(0);

    for (int t = 0; t < 63; ++t) {
        const int sb  = ((t & 1) ^ 1) * 32768;  // u16 index of stage buffer
        const int kt1 = (t + 1) * 64;
        PH32(0, 0, 1, 1, stageA(sb, 0, kt1), 0);
        PH32(0, 1, 0, 1, stageB(sb, 0, kt1), 0);
        PH32(1, 1, 1, 0, stageB(sb, 1, kt1), 0);
        PH32(1, 0, 0, 0, stageA(sb, 1, kt1), 1);
        #pragma unroll
        for (int i = 0; i < 4; ++i) ab2[i] ^= 65536;
        bb2[0] ^= 65536; bb2[1] ^= 65536;
    }
    // tail tile 63 (bases already point at buf1), no staging
    asm volatile("s_waitcnt vmcnt(0)" ::: "memory");
    __builtin_amdgcn_s_barrier();
    __builtin_amdgcn_sched_barrier(0);
    PH32(0, 0, 1, 1, (void)0, 0);
    PH32(0, 1, 0, 1, (void)0, 0);
    PH32(1, 1, 1, 0, (void)0, 0);
    PH32(1, 0, 0, 0, (void)0, 0);

    // epilogue: C/D col = lane&31, row = (reg&3) + 8*(reg>>2) + 4*(lane>>5)
    const int orow0 = tm * 256 + wr * 128 + hb * 4;
    const int ocol0 = tn * 256 + wc * 64 + l31;
    #pragma unroll
    for (int mt = 0; mt < 4; ++mt) {
        #pragma unroll
        for (int nt = 0; nt < 2; ++nt) {
            #pragma unroll
            for (int reg = 0; reg < 16; ++reg) {
                const int row = orow0 + mt * 32 + (reg & 3) + 8 * (reg >> 2);
                const int col = ocol0 + nt * 32;
                float v = acc[mt][nt][reg];
                if (MODE == 1) {
                    v = fmaxf(v, 0.0f) * 2.0f;
                    ((unsigned short*)Cout)[((size_t)row << 12) + col] = f2bf(v);
                } else {
                    ((float*)Cout)[((size_t)row << 12) + col] = v;
                }
            }
        }
    }
}

// ---------------------------------------------------------------------------
extern "C" void kernel_launch(void* const* d_in, const int* in_sizes, int n_in,
                              void* d_out, int out_size, void* d_ws, size_t ws_size,
                              hipStream_t stream) {
    const float* x  = (const float*)d_in[0];
    const void*  k0 = d_in[1];
    const float* s0 = (const float*)d_in[2];
    const void*  k1 = d_in[3];
    const float* s1 = (const float*)d_in[4];
    const void*  k2 = d_in[5];
    const float* s2 = (const float*)d_in[6];

    const int M = in_sizes[0] / DD;   // 8192

    const size_t act_bytes = (size_t)M * DD * 2;
    const size_t w_bytes   = (size_t)DD * DD * 2;
    const size_t need      = act_bytes * 2 + w_bytes + 256;
    if (ws_size < need) return;

    char* ws = (char*)d_ws;
    unsigned short* xb = (unsigned short*)ws;                        // M x DD bf16 (later h2)
    unsigned short* h1 = (unsigned short*)(ws + act_bytes);          // M x DD bf16
    unsigned short* wt = (unsigned short*)(ws + act_bytes * 2);      // DD x DD bf16 (N x K)
    int* flag          = (int*)(ws + act_bytes * 2 + w_bytes);

    detect_kernel<<<1, 64, 0, stream>>>((const unsigned int*)k0, flag);
    pack_x_kernel<<<2048, 256, 0, stream>>>(x, xb, M * DD / 8);

    dim3 pw_grid(DD / 64, DD / 64);
    const int gemm_grid = (M / 256) * (DD / 256);   // 512

    // layer 0: h1 = relu(s0 * x @ W0) * 2
    pack_w_kernel<<<pw_grid, 256, 0, stream>>>(k0, wt, s0, 1.0f, DD, flag);
    gemm256_kernel<1><<<gemm_grid, 512, 0, stream>>>(xb, wt, h1);

    // layer 1: h2 = relu(ei_dense(h1, k1, s1)) * 2
    pack_w_kernel<<<pw_grid, 256, 0, stream>>>(k1, wt, s1, -4.0f, NE_IDX, flag);
    gemm256_kernel<1><<<gemm_grid, 512, 0, stream>>>(h1, wt, xb);

    // layer 2: out = ei_dense(h2, k2, s2), fp32
    pack_w_kernel<<<pw_grid, 256, 0, stream>>>(k2, wt, s2, -4.0f, NE_IDX, flag);
    gemm256_kernel<0><<<gemm_grid, 512, 0, stream>>>(xb, wt, (float*)d_out);
}